// Round 5
// baseline (82.938 us; speedup 1.0000x reference)
//
#include <hip/hip_runtime.h>
#include <math.h>

#define NB 768
#define ND 128
#define NC 12            // NB / 64 lane-chunks
#define APB 3            // anchors per block -> grid = 256 (one per CU)
#define TJ 128           // j-rows per LDS tile
#define NT 6             // NB / TJ
#define TSTR 129         // padded tile row stride in floats (bank-conflict-free)
#define TL_MARGIN 1.0f
#define TL_EPS 1e-12f

// d_ws layout: float psum[NB]; float pcnt[NB];

__global__ __launch_bounds__(256) void triplet_fused_kernel(
    const float* __restrict__ E, const int* __restrict__ L,
    float* __restrict__ psum, float* __restrict__ pcnt)
{
    extern __shared__ float tile[];        // [TJ][TSTR] = 66048 B dynamic
    __shared__ float arow[APB][ND];        // 1.5 KB
    __shared__ float s_sqi[APB];

    const int i0   = blockIdx.x * APB;
    const int tid  = threadIdx.x;
    const int lane = tid & 63;
    const int wave = tid >> 6;             // waves 0..2 = anchors, wave 3 helps stage

    // stage the 3 anchor rows (contiguous, coalesced): 96 float4
    if (tid < APB * ND / 4)
        ((float4*)arow)[tid] = ((const float4*)(E + (size_t)i0 * ND))[tid];

    // labels straight from global (L2-hot, coalesced) -> masks
    const int ia = i0 + ((wave < APB) ? wave : 0);
    const int li = L[ia];
    unsigned negm = 0u, posm = 0u;
    #pragma unroll
    for (int c = 0; c < NC; ++c) {
        int j = c * 64 + lane;
        int lj = L[j];
        if (lj != li)     negm |= (1u << c);
        else if (j != ia) posm |= (1u << c);
    }
    __syncthreads();

    // sq(anchor) per wave via shuffle reduce
    float sqi = 0.f;
    if (wave < APB) {
        float v0 = arow[wave][lane], v1 = arow[wave][lane + 64];
        float s = v0 * v0 + v1 * v1;
        #pragma unroll
        for (int off = 32; off > 0; off >>= 1) s += __shfl_xor(s, off);
        if (lane == 0) s_sqi[wave] = s;
    }
    __syncthreads();
    if (wave < APB) sqi = s_sqi[wave];

    // ---- tiled distance phase: distances land directly in dk[] registers ----
    float dk[NC];
    const float4* arp = (const float4*)arow[(wave < APB) ? wave : 0];

    #pragma unroll
    for (int t = 0; t < NT; ++t) {
        __syncthreads();   // previous tile fully consumed
        // stage tile t: 128 rows x 128 floats, coalesced float4, all 256 threads
        {
            const float4* src = (const float4*)(E + (size_t)t * TJ * ND);
            #pragma unroll
            for (int ii = 0; ii < 16; ++ii) {
                int idx = tid + ii * 256;          // 0..4095 float4
                int row = idx >> 5;                // 32 float4 per row
                int c4  = idx & 31;
                float4 v = src[idx];
                *(float4*)&tile[row * TSTR + c4 * 4] = v;
            }
        }
        __syncthreads();
        if (wave < APB) {
            const float4* r0p = (const float4*)&tile[lane * TSTR];
            const float4* r1p = (const float4*)&tile[(lane + 64) * TSTR];
            float d0 = 0.f, s0 = 0.f, d1 = 0.f, s1 = 0.f;
            #pragma unroll
            for (int k = 0; k < 32; ++k) {
                float4 a = arp[k];
                float4 x = r0p[k];
                float4 y = r1p[k];
                d0 += a.x * x.x + a.y * x.y + a.z * x.z + a.w * x.w;
                s0 += x.x * x.x + x.y * x.y + x.z * x.z + x.w * x.w;
                d1 += a.x * y.x + a.y * y.y + a.z * y.z + a.w * y.w;
                s1 += y.x * y.x + y.y * y.y + y.z * y.z + y.w * y.w;
            }
            dk[2 * t]     = sqrtf(fmaxf(sqi + s0 - 2.f * d0, TL_EPS));
            dk[2 * t + 1] = sqrtf(fmaxf(sqi + s1 - 2.f * d1, TL_EPS));
        }
    }

    // ---- mining: wave a mines anchor i0+a, fully wave-local in registers ----
    if (wave < APB) {
        // hardest-negative value (min over negatives)
        float bv = INFINITY;
        #pragma unroll
        for (int c = 0; c < NC; ++c)
            if ((negm >> c) & 1u) bv = fminf(bv, dk[c]);
        #pragma unroll
        for (int off = 32; off > 0; off >>= 1)
            bv = fminf(bv, __shfl_xor(bv, off));
        const float hval = bv;

        float lsum = 0.f, lcnt = 0.f;
        if (isfinite(hval)) {
            #pragma unroll
            for (int c = 0; c < NC; ++c) {
                unsigned long long pm = __ballot((posm >> c) & 1u);
                while (pm) {
                    const int sl = __builtin_ctzll(pm);
                    pm &= pm - 1;
                    const float pd = __shfl(dk[c], sl);
                    float nd = hval;
                    #pragma unroll
                    for (int c2 = 0; c2 < NC; ++c2) {
                        bool pred = ((negm >> c2) & 1u) &&
                                    (dk[c2] > pd) && (dk[c2] < pd + TL_MARGIN);
                        unsigned long long m = __ballot(pred);
                        if (m) { nd = __shfl(dk[c2], __builtin_ctzll(m)); break; }
                    }
                    lsum += fmaxf(pd - nd + TL_MARGIN, 0.f);
                    lcnt += 1.f;
                }
            }
        }
        if (lane == 0) { psum[ia] = lsum; pcnt[ia] = lcnt; }
    }
}

__global__ __launch_bounds__(64) void triplet_finalize_kernel(
    const float* __restrict__ psum, const float* __restrict__ pcnt,
    float* __restrict__ out)
{
    const int lane = threadIdx.x;
    float a = 0.f, b = 0.f;
    for (int j = lane; j < NB; j += 64) { a += psum[j]; b += pcnt[j]; }
    #pragma unroll
    for (int off = 32; off > 0; off >>= 1) {
        a += __shfl_xor(a, off);
        b += __shfl_xor(b, off);
    }
    if (lane == 0) out[0] = a / fmaxf(b, 1.f);
}

extern "C" void kernel_launch(void* const* d_in, const int* in_sizes, int n_in,
                              void* d_out, int out_size, void* d_ws, size_t ws_size,
                              hipStream_t stream) {
    const float* E = (const float*)d_in[0];
    const int*   L = (const int*)d_in[1];
    float* psum = (float*)d_ws;
    float* pcnt = psum + NB;
    float* out  = (float*)d_out;

    const int dyn_lds = TJ * TSTR * (int)sizeof(float);   // 66048 B
    (void)hipFuncSetAttribute((const void*)triplet_fused_kernel,
                              hipFuncAttributeMaxDynamicSharedMemorySize, dyn_lds);

    triplet_fused_kernel<<<NB / APB, 256, dyn_lds, stream>>>(E, L, psum, pcnt);
    triplet_finalize_kernel<<<1, 64, 0, stream>>>(psum, pcnt, out);
}

// Round 6
// 34.754 us; speedup vs baseline: 2.3864x; 2.3864x over previous
//
#include <hip/hip_runtime.h>
#include <math.h>

#define NB 768
#define ND 128
#define NC 12            // NB / 64 lane-chunks
#define TL_MARGIN 1.0f
#define TL_EPS 1e-12f

// ws layout (bytes):
//   ET   @ 0x000000 : 128*768 f32 = 384 KB   (ET[k][j] = E[j][k])
//   D    @ 0x100000 : 768*768 f32 = 2.25 MB
//   psum @ 0x400000 : 768 f32
//   pcnt @ 0x400000 + 3072 : 768 f32

// ---- K0: transpose E (768x128) -> ET (128x768), 12 blocks x 64 rows ----
__global__ __launch_bounds__(256) void transpose_kernel(
    const float* __restrict__ E, float* __restrict__ ET)
{
    __shared__ float tile[64][129];
    const int b   = blockIdx.x;
    const int tid = threadIdx.x;
    const float4* src = (const float4*)(E + (size_t)b * 64 * ND);
    #pragma unroll
    for (int i = 0; i < 8; ++i) {
        int idx = tid + i * 256;          // 0..2047 float4
        int row = idx >> 5;               // 32 float4 per row
        int c4  = idx & 31;
        float4 v = src[idx];              // coalesced
        tile[row][c4 * 4 + 0] = v.x;
        tile[row][c4 * 4 + 1] = v.y;
        tile[row][c4 * 4 + 2] = v.z;
        tile[row][c4 * 4 + 3] = v.w;
    }
    __syncthreads();
    const int lane = tid & 63;
    const int kw   = tid >> 6;
    #pragma unroll
    for (int kk = 0; kk < 32; ++kk) {
        int k = kk * 4 + kw;
        // LDS read: bank (lane + k) % 32 -> 2-way (free); store coalesced 256B
        ET[(size_t)k * NB + b * 64 + lane] = tile[lane][k];
    }
}

// ---- K1: D[a][j] = dist, register-blocked; 288 blocks = 48 a-tiles x 6 j-tiles
__global__ __launch_bounds__(256) void dist_kernel(
    const float* __restrict__ E, const float* __restrict__ ET,
    float* __restrict__ D)
{
    const int tid  = threadIdx.x;
    const int lane = tid & 63;
    const int wave = tid >> 6;
    const int bi   = blockIdx.x;
    const int jt   = (bi % 6) * 128;
    int a0 = (bi / 6) * 16 + wave * 4;
    a0 = __builtin_amdgcn_readfirstlane(a0);     // wave-uniform -> SGPR

    // anchor squared norms (coalesced reads + wave reduce; uniform result)
    float sqa0, sqa1, sqa2, sqa3;
    {
        float s0, s1, s2, s3;
        { float v0 = E[(size_t)(a0+0)*ND + lane], v1 = E[(size_t)(a0+0)*ND + lane + 64]; s0 = v0*v0 + v1*v1; }
        { float v0 = E[(size_t)(a0+1)*ND + lane], v1 = E[(size_t)(a0+1)*ND + lane + 64]; s1 = v0*v0 + v1*v1; }
        { float v0 = E[(size_t)(a0+2)*ND + lane], v1 = E[(size_t)(a0+2)*ND + lane + 64]; s2 = v0*v0 + v1*v1; }
        { float v0 = E[(size_t)(a0+3)*ND + lane], v1 = E[(size_t)(a0+3)*ND + lane + 64]; s3 = v0*v0 + v1*v1; }
        #pragma unroll
        for (int off = 32; off > 0; off >>= 1) {
            s0 += __shfl_xor(s0, off);
            s1 += __shfl_xor(s1, off);
            s2 += __shfl_xor(s2, off);
            s3 += __shfl_xor(s3, off);
        }
        sqa0 = s0; sqa1 = s1; sqa2 = s2; sqa3 = s3;
    }

    const float* A0 = E + (size_t)(a0 + 0) * ND;   // uniform base -> s_load
    const float* A1 = E + (size_t)(a0 + 1) * ND;
    const float* A2 = E + (size_t)(a0 + 2) * ND;
    const float* A3 = E + (size_t)(a0 + 3) * ND;

    float p0x = 0.f, p0y = 0.f, p1x = 0.f, p1y = 0.f;
    float p2x = 0.f, p2y = 0.f, p3x = 0.f, p3y = 0.f;
    float sjx = 0.f, sjy = 0.f;
    const float* Bbase = ET + jt + lane * 2;

    #pragma unroll 8
    for (int k = 0; k < ND; ++k) {
        float2 bv = *(const float2*)(Bbase + (size_t)k * NB);  // coalesced 512B
        float a0v = A0[k], a1v = A1[k], a2v = A2[k], a3v = A3[k];
        p0x += a0v * bv.x; p0y += a0v * bv.y;
        p1x += a1v * bv.x; p1y += a1v * bv.y;
        p2x += a2v * bv.x; p2y += a2v * bv.y;
        p3x += a3v * bv.x; p3y += a3v * bv.y;
        sjx += bv.x * bv.x; sjy += bv.y * bv.y;
    }

    const int j0 = jt + lane * 2;
    {
        float dx = sqrtf(fmaxf(sqa0 + sjx - 2.f * p0x, TL_EPS));
        float dy = sqrtf(fmaxf(sqa0 + sjy - 2.f * p0y, TL_EPS));
        *(float2*)&D[(size_t)(a0 + 0) * NB + j0] = make_float2(dx, dy);
    }
    {
        float dx = sqrtf(fmaxf(sqa1 + sjx - 2.f * p1x, TL_EPS));
        float dy = sqrtf(fmaxf(sqa1 + sjy - 2.f * p1y, TL_EPS));
        *(float2*)&D[(size_t)(a0 + 1) * NB + j0] = make_float2(dx, dy);
    }
    {
        float dx = sqrtf(fmaxf(sqa2 + sjx - 2.f * p2x, TL_EPS));
        float dy = sqrtf(fmaxf(sqa2 + sjy - 2.f * p2y, TL_EPS));
        *(float2*)&D[(size_t)(a0 + 2) * NB + j0] = make_float2(dx, dy);
    }
    {
        float dx = sqrtf(fmaxf(sqa3 + sjx - 2.f * p3x, TL_EPS));
        float dy = sqrtf(fmaxf(sqa3 + sjy - 2.f * p3y, TL_EPS));
        *(float2*)&D[(size_t)(a0 + 3) * NB + j0] = make_float2(dx, dy);
    }
}

// ---- K2: mining (wave per anchor, register row cache + ballots) ----
__global__ __launch_bounds__(256) void mine_kernel(
    const float* __restrict__ D, const int* __restrict__ L,
    float* __restrict__ psum, float* __restrict__ pcnt)
{
    const int tid  = threadIdx.x;
    const int lane = tid & 63;
    const int wave = tid >> 6;
    const int ia   = blockIdx.x * 4 + wave;
    const int li   = L[ia];

    float dk[NC];
    unsigned negm = 0u, posm = 0u;
    #pragma unroll
    for (int c = 0; c < NC; ++c) {
        int j = c * 64 + lane;
        dk[c] = D[(size_t)ia * NB + j];       // coalesced 256B
        int lj = L[j];
        if (lj != li)     negm |= (1u << c);
        else if (j != ia) posm |= (1u << c);
    }

    // hardest-negative value (min over negatives)
    float bv = INFINITY;
    #pragma unroll
    for (int c = 0; c < NC; ++c)
        if ((negm >> c) & 1u) bv = fminf(bv, dk[c]);
    #pragma unroll
    for (int off = 32; off > 0; off >>= 1)
        bv = fminf(bv, __shfl_xor(bv, off));
    const float hval = bv;

    float lsum = 0.f, lcnt = 0.f;
    if (isfinite(hval)) {
        #pragma unroll
        for (int c = 0; c < NC; ++c) {
            unsigned long long pm = __ballot((posm >> c) & 1u);
            while (pm) {
                const int sl = __builtin_ctzll(pm);
                pm &= pm - 1;
                const float pd = __shfl(dk[c], sl);
                float nd = hval;
                #pragma unroll
                for (int c2 = 0; c2 < NC; ++c2) {
                    bool pred = ((negm >> c2) & 1u) &&
                                (dk[c2] > pd) && (dk[c2] < pd + TL_MARGIN);
                    unsigned long long m = __ballot(pred);
                    if (m) { nd = __shfl(dk[c2], __builtin_ctzll(m)); break; }
                }
                lsum += fmaxf(pd - nd + TL_MARGIN, 0.f);
                lcnt += 1.f;
            }
        }
    }
    if (lane == 0) { psum[ia] = lsum; pcnt[ia] = lcnt; }
}

__global__ __launch_bounds__(64) void triplet_finalize_kernel(
    const float* __restrict__ psum, const float* __restrict__ pcnt,
    float* __restrict__ out)
{
    const int lane = threadIdx.x;
    float a = 0.f, b = 0.f;
    for (int j = lane; j < NB; j += 64) { a += psum[j]; b += pcnt[j]; }
    #pragma unroll
    for (int off = 32; off > 0; off >>= 1) {
        a += __shfl_xor(a, off);
        b += __shfl_xor(b, off);
    }
    if (lane == 0) out[0] = a / fmaxf(b, 1.f);
}

extern "C" void kernel_launch(void* const* d_in, const int* in_sizes, int n_in,
                              void* d_out, int out_size, void* d_ws, size_t ws_size,
                              hipStream_t stream) {
    const float* E = (const float*)d_in[0];
    const int*   L = (const int*)d_in[1];
    char* ws = (char*)d_ws;
    float* ET   = (float*)(ws);
    float* D    = (float*)(ws + 0x100000);
    float* psum = (float*)(ws + 0x400000);
    float* pcnt = psum + NB;
    float* out  = (float*)d_out;

    transpose_kernel<<<NB / 64, 256, 0, stream>>>(E, ET);
    dist_kernel<<<(NB / 16) * 6, 256, 0, stream>>>(E, ET, D);
    mine_kernel<<<NB / 4, 256, 0, stream>>>(D, L, psum, pcnt);
    triplet_finalize_kernel<<<1, 64, 0, stream>>>(psum, pcnt, out);
}